// Round 18
// baseline (281.103 us; speedup 1.0000x reference)
//
#include <hip/hip_runtime.h>

typedef __bf16 bf16;
typedef __attribute__((ext_vector_type(4))) __bf16 bf16x4;
typedef __attribute__((ext_vector_type(8))) __bf16 bf16x8;
typedef __attribute__((ext_vector_type(4))) float f32x4;

#define MFMA16(a, b, c) __builtin_amdgcn_mfma_f32_16x16x32_bf16((a), (b), (c), 0, 0, 0)

constexpr int N   = 8192;
constexpr int HID = 64;

// ---------------- shared pipeline pieces (R17-proven) ----------------
// Block = 4 waves on the same 16 output rows; per-wave reg-staged pipeline,
// A 4-deep (float4->cvt->LDS swizzled), B 4-deep reg fragments, no barriers.

// pass0: C=(x@W1); inline epilogue writes C^T bf16 (S1T). gridDim.y==1.
__global__ __launch_bounds__(256) void gcn_pass0(const float* __restrict__ A, int K,
                                                 const bf16* __restrict__ Bt,
                                                 bf16* __restrict__ outT) {
  __shared__ bf16  As[4][2][16 * 64];
  __shared__ float Hred[4][16][68];
  __shared__ float Ht[16][72];
  const int tid = threadIdx.x, lane = tid & 63, w = tid >> 6;
  const int r = lane & 15, hi = lane >> 4;
  const int i0 = blockIdx.x * 16;
  const int Kw = K >> 2, kb0 = w * Kw, nt = Kw / 64;
  const int aR = hi, aC = r * 4;

  float4 ra[4][4];
  bf16x8 rb[4][8];
  f32x4 acc[4] = {};

  auto loadA = [&](float4 (&dst)[4], int t) {
    const int k0 = kb0 + t * 64;
#pragma unroll
    for (int s = 0; s < 4; ++s)
      dst[s] = *reinterpret_cast<const float4*>(&A[(size_t)(i0 + 4 * s + aR) * K + k0 + aC]);
  };
  auto loadB = [&](bf16x8 (&dst)[8], int t) {
    const int k0 = kb0 + t * 64;
#pragma unroll
    for (int n = 0; n < 4; ++n)
#pragma unroll
      for (int kk = 0; kk < 2; ++kk)
        dst[n * 2 + kk] = *reinterpret_cast<const bf16x8*>(
            &Bt[(size_t)(n * 16 + r) * K + k0 + kk * 32 + hi * 8]);
  };
  auto writeA = [&](int buf, const float4 (&src)[4]) {
    char* base = (char*)&As[w][buf][0];
#pragma unroll
    for (int s = 0; s < 4; ++s) {
      const int R = 4 * s + aR;
      bf16x4 o;
      o[0] = (bf16)src[s].x; o[1] = (bf16)src[s].y;
      o[2] = (bf16)src[s].z; o[3] = (bf16)src[s].w;
      *reinterpret_cast<bf16x4*>(base + R * 128 + ((aC * 2) ^ ((R & 7) << 4))) = o;
    }
  };
  auto compute = [&](int buf, const bf16x8 (&rbv)[8]) {
    const char* base = (const char*)&As[w][buf][0];
#pragma unroll
    for (int kk = 0; kk < 2; ++kk) {
      const bf16x8 fa = *reinterpret_cast<const bf16x8*>(
          base + r * 128 + ((kk * 64 + hi * 16) ^ ((r & 7) << 4)));
#pragma unroll
      for (int n = 0; n < 4; ++n)
        acc[n] = MFMA16(fa, rbv[n * 2 + kk], acc[n]);
    }
  };

  loadA(ra[0], 0);
  if (nt > 1) loadA(ra[1], 1);
  if (nt > 2) loadA(ra[2], 2);
  if (nt > 3) loadA(ra[3], 3);
  loadB(rb[0], 0);
  if (nt > 1) loadB(rb[1], 1);
  if (nt > 2) loadB(rb[2], 2);
  writeA(0, ra[0]);

  for (int tb = 0; tb < nt; tb += 4) {
#pragma unroll
    for (int u = 0; u < 4; ++u) {
      const int t = tb + u;
      if (t >= nt) continue;
      if (t + 3 < nt) loadB(rb[(u + 3) & 3], t + 3);
      if (t + 4 < nt) loadA(ra[u & 3], t + 4);
      if (t + 1 < nt) writeA((u + 1) & 1, ra[(u + 1) & 3]);
      compute(u & 1, rb[u & 3]);
    }
  }

  // C/D layout (m89-verified): col = lane&15, row = (lane>>4)*4 + reg
#pragma unroll
  for (int n = 0; n < 4; ++n)
#pragma unroll
    for (int g = 0; g < 4; ++g)
      Hred[w][hi * 4 + g][n * 16 + r] = acc[n][g];
  __syncthreads();
  {
    const int row = tid >> 4, c4 = (tid & 15) * 4;
    float4 s = {0.f, 0.f, 0.f, 0.f};
#pragma unroll
    for (int q = 0; q < 4; ++q) {
      const float4 v = *reinterpret_cast<const float4*>(&Hred[q][row][c4]);
      s.x += v.x; s.y += v.y; s.z += v.z; s.w += v.w;
    }
    *reinterpret_cast<float4*>(&Ht[row][c4]) = s;
  }
  __syncthreads();
  // transpose-store: outT[j][i0..i0+16]
  const int j = tid >> 2, iq = tid & 3;
  bf16x4 o;
#pragma unroll
  for (int e = 0; e < 4; ++e) o[e] = (bf16)Ht[iq * 4 + e][j];
  *reinterpret_cast<bf16x4*>(&outT[(size_t)j * N + i0 + iq * 4]) = o;
}

// adj passes: grid (512, 2). Block (bx,by): rows 16bx, K-half by; waves split
// the half. Writes RAW 16x64 f32 partial tile to pPart[by] (no epilogue).
__global__ __launch_bounds__(256) void gcn_partial(const float* __restrict__ A, int K,
                                                   const bf16* __restrict__ Bt,
                                                   float* __restrict__ pPart) {
  __shared__ bf16  As[4][2][16 * 64];
  __shared__ float Hred[4][16][68];
  __shared__ float Ht[16][72];
  const int tid = threadIdx.x, lane = tid & 63, w = tid >> 6;
  const int r = lane & 15, hi = lane >> 4;
  const int i0 = blockIdx.x * 16;
  const int Kslab = K / gridDim.y;
  const int Kw = Kslab >> 2;
  const int kb0 = blockIdx.y * Kslab + w * Kw;
  const int nt = Kw / 64;
  const int aR = hi, aC = r * 4;

  float4 ra[4][4];
  bf16x8 rb[4][8];
  f32x4 acc[4] = {};

  auto loadA = [&](float4 (&dst)[4], int t) {
    const int k0 = kb0 + t * 64;
#pragma unroll
    for (int s = 0; s < 4; ++s)
      dst[s] = *reinterpret_cast<const float4*>(&A[(size_t)(i0 + 4 * s + aR) * K + k0 + aC]);
  };
  auto loadB = [&](bf16x8 (&dst)[8], int t) {
    const int k0 = kb0 + t * 64;
#pragma unroll
    for (int n = 0; n < 4; ++n)
#pragma unroll
      for (int kk = 0; kk < 2; ++kk)
        dst[n * 2 + kk] = *reinterpret_cast<const bf16x8*>(
            &Bt[(size_t)(n * 16 + r) * K + k0 + kk * 32 + hi * 8]);
  };
  auto writeA = [&](int buf, const float4 (&src)[4]) {
    char* base = (char*)&As[w][buf][0];
#pragma unroll
    for (int s = 0; s < 4; ++s) {
      const int R = 4 * s + aR;
      bf16x4 o;
      o[0] = (bf16)src[s].x; o[1] = (bf16)src[s].y;
      o[2] = (bf16)src[s].z; o[3] = (bf16)src[s].w;
      *reinterpret_cast<bf16x4*>(base + R * 128 + ((aC * 2) ^ ((R & 7) << 4))) = o;
    }
  };
  auto compute = [&](int buf, const bf16x8 (&rbv)[8]) {
    const char* base = (const char*)&As[w][buf][0];
#pragma unroll
    for (int kk = 0; kk < 2; ++kk) {
      const bf16x8 fa = *reinterpret_cast<const bf16x8*>(
          base + r * 128 + ((kk * 64 + hi * 16) ^ ((r & 7) << 4)));
#pragma unroll
      for (int n = 0; n < 4; ++n)
        acc[n] = MFMA16(fa, rbv[n * 2 + kk], acc[n]);
    }
  };

  loadA(ra[0], 0);
  loadA(ra[1], 1);
  loadA(ra[2], 2);
  loadA(ra[3], 3);
  loadB(rb[0], 0);
  loadB(rb[1], 1);
  loadB(rb[2], 2);
  writeA(0, ra[0]);

  for (int tb = 0; tb < nt; tb += 4) {
#pragma unroll
    for (int u = 0; u < 4; ++u) {
      const int t = tb + u;
      if (t + 3 < nt) loadB(rb[(u + 3) & 3], t + 3);
      if (t + 4 < nt) loadA(ra[u & 3], t + 4);
      if (t + 1 < nt) writeA((u + 1) & 1, ra[(u + 1) & 3]);
      compute(u & 1, rb[u & 3]);
    }
  }

  // cross-wave reduce -> raw partial tile (float4 rows, 256B contiguous chunks)
#pragma unroll
  for (int n = 0; n < 4; ++n)
#pragma unroll
    for (int g = 0; g < 4; ++g)
      Hred[w][hi * 4 + g][n * 16 + r] = acc[n][g];
  __syncthreads();
  {
    const int row = tid >> 4, c4 = (tid & 15) * 4;
    float4 s = {0.f, 0.f, 0.f, 0.f};
#pragma unroll
    for (int q = 0; q < 4; ++q) {
      const float4 v = *reinterpret_cast<const float4*>(&Hred[q][row][c4]);
      s.x += v.x; s.y += v.y; s.z += v.z; s.w += v.w;
    }
    float* dst = pPart + (size_t)blockIdx.y * N * HID;
    *reinterpret_cast<float4*>(&dst[(size_t)(i0 + row) * HID + c4]) = s;
  }
}

// h1T[j][i] = relu(sum_s pB[s][i][j]) bf16 (reduce + relu + transpose), 128 blocks
__global__ __launch_bounds__(256) void reduce_relu_T(const float* __restrict__ pB,
                                                     bf16* __restrict__ h1T) {
  __shared__ float t[64][65];
  const int i0 = blockIdx.x * 64;
  const int tid = threadIdx.x;
#pragma unroll
  for (int s = 0; s < 4; ++s) {
    const int idx = tid + s * 256;
    const int row = idx >> 4, c4 = idx & 15;
    const size_t off = (size_t)(i0 + row) * HID + c4 * 4;
    const float4 v0 = *reinterpret_cast<const float4*>(&pB[off]);
    const float4 v1 = *reinterpret_cast<const float4*>(&pB[(size_t)N * HID + off]);
    t[row][c4 * 4 + 0] = fmaxf(v0.x + v1.x, 0.f);
    t[row][c4 * 4 + 1] = fmaxf(v0.y + v1.y, 0.f);
    t[row][c4 * 4 + 2] = fmaxf(v0.z + v1.z, 0.f);
    t[row][c4 * 4 + 3] = fmaxf(v0.w + v1.w, 0.f);
  }
  __syncthreads();
#pragma unroll
  for (int s = 0; s < 2; ++s) {
    const int idx = tid + s * 256;
    const int j = idx >> 3, q = idx & 7;
    bf16x8 o;
#pragma unroll
    for (int e = 0; e < 8; ++e) o[e] = (bf16)t[q * 8 + e][j];
    *reinterpret_cast<bf16x8*>(&h1T[(size_t)j * N + i0 + q * 8]) = o;
  }
}

// t = sum_s pC[s]; mu = t@W2, lv = t@W3 (f32), 128 blocks
__global__ __launch_bounds__(256) void reduce_w23_mulv(const float* __restrict__ pC,
                                                       const float* __restrict__ W2,
                                                       const float* __restrict__ W3,
                                                       float* __restrict__ mu,
                                                       float* __restrict__ lv) {
  __shared__ float Hs[64][65];
  __shared__ float Ws[64][128];
  const int i0 = blockIdx.x * 64;
  const int tid = threadIdx.x;
#pragma unroll
  for (int s = 0; s < 32; ++s) {
    const int idx = tid + s * 256;
    const int c = idx >> 7, j = idx & 127;
    Ws[c][j] = (j < 64) ? W2[c * HID + j] : W3[c * HID + (j - 64)];
  }
#pragma unroll
  for (int s8 = 0; s8 < 16; ++s8) {
    const int idx = tid + s8 * 256;
    const int rr = idx >> 6, c = idx & 63;
    const size_t off = (size_t)(i0 + rr) * HID + c;
    Hs[rr][c] = pC[off] + pC[(size_t)N * HID + off];
  }
  __syncthreads();
  const int j = tid & 127, ih = tid >> 7;
  for (int ii = ih; ii < 64; ii += 2) {
    float a = 0.0f;
#pragma unroll
    for (int c = 0; c < 64; ++c) a += Hs[ii][c] * Ws[c][j];
    if (j < 64)
      mu[(size_t)(i0 + ii) * HID + j] = a;
    else
      lv[(size_t)(i0 + ii) * HID + (j - 64)] = a;
  }
}

// W1 [256][64] f32 -> W1T [64][256] bf16
__global__ void prep_w1t(const float* __restrict__ W1, bf16* __restrict__ W1T) {
  const int idx = blockIdx.x * 256 + threadIdx.x;  // 16384
  const int j = idx >> 8, k = idx & 255;
  W1T[idx] = (bf16)W1[k * HID + j];
}

// recon[i][j] = dot(mu[i,:], mu[j,:]) ; K=64, write-bound.
constexpr int LDT = 72;
__global__ __launch_bounds__(256) void recon_mm(const float* __restrict__ mu,
                                                float* __restrict__ out) {
  __shared__ alignas(16) char pool[128 * LDT * 2 * 2];  // 36864 B: Am|Bm, then Ct
  bf16* Am = (bf16*)pool;                                // [128][72]
  bf16* Bm = (bf16*)(pool + 128 * LDT * 2);              // [128][72]
  float* Ct = (float*)pool;                              // [64][132] = 33792 B
  const int tid = threadIdx.x, lane = tid & 63, wave = tid >> 6;
  const int i0 = blockIdx.x * 128, j0 = blockIdx.y * 128;
  {
    const int rr = tid >> 4, c4 = tid & 15;
#pragma unroll
    for (int s = 0; s < 8; ++s) {
      const int row = rr + s * 16;
      const float4 v = *reinterpret_cast<const float4*>(&mu[(size_t)(i0 + row) * HID + c4 * 4]);
      bf16x4 o;
      o[0] = (bf16)v.x; o[1] = (bf16)v.y; o[2] = (bf16)v.z; o[3] = (bf16)v.w;
      *reinterpret_cast<bf16x4*>(&Am[row * LDT + c4 * 4]) = o;
      const float4 u = *reinterpret_cast<const float4*>(&mu[(size_t)(j0 + row) * HID + c4 * 4]);
      bf16x4 p;
      p[0] = (bf16)u.x; p[1] = (bf16)u.y; p[2] = (bf16)u.z; p[3] = (bf16)u.w;
      *reinterpret_cast<bf16x4*>(&Bm[row * LDT + c4 * 4]) = p;
    }
  }
  __syncthreads();
  f32x4 acc[2][8] = {};
  const int rA = wave * 32 + (lane & 15);
#pragma unroll
  for (int kk = 0; kk < 2; ++kk) {
    const int kb = kk * 32 + ((lane >> 4) << 3);
    const bf16x8 a0 = *reinterpret_cast<const bf16x8*>(&Am[rA * LDT + kb]);
    const bf16x8 a1 = *reinterpret_cast<const bf16x8*>(&Am[(rA + 16) * LDT + kb]);
#pragma unroll
    for (int n = 0; n < 8; ++n) {
      const bf16x8 b = *reinterpret_cast<const bf16x8*>(&Bm[(n * 16 + (lane & 15)) * LDT + kb]);
      acc[0][n] = MFMA16(a0, b, acc[0][n]);
      acc[1][n] = MFMA16(a1, b, acc[1][n]);
    }
  }
  const int r4 = (lane >> 4) << 2, c = lane & 15;
#pragma unroll
  for (int h = 0; h < 2; ++h) {
    __syncthreads();
    if ((wave >> 1) == h) {
      const int rbase = (wave & 1) * 32;
#pragma unroll
      for (int m = 0; m < 2; ++m)
#pragma unroll
        for (int n = 0; n < 8; ++n)
#pragma unroll
          for (int g = 0; g < 4; ++g)
            Ct[(rbase + m * 16 + r4 + g) * 132 + n * 16 + c] = acc[m][n][g];
    }
    __syncthreads();
#pragma unroll
    for (int s = 0; s < 8; ++s) {
      const int idx = tid + s * 256;
      const int row = idx >> 5, q = idx & 31;
      const float4 v = *reinterpret_cast<const float4*>(&Ct[row * 132 + q * 4]);
      *reinterpret_cast<float4*>(&out[(size_t)(i0 + h * 64 + row) * N + j0 + q * 4]) = v;
    }
  }
}

extern "C" void kernel_launch(void* const* d_in, const int* in_sizes, int n_in, void* d_out,
                              int out_size, void* d_ws, size_t ws_size, hipStream_t stream) {
  const float* x   = (const float*)d_in[0];
  const float* adj = (const float*)d_in[1];
  const float* W1  = (const float*)d_in[2];
  const float* W2  = (const float*)d_in[3];
  const float* W3  = (const float*)d_in[4];

  float* out    = (float*)d_out;
  float* recon  = out;                          // [8192][8192] 256 MiB
  float* mu_out = out + (size_t)N * N;          // outside recon region
  float* lv_out = mu_out + (size_t)N * HID;

  // Scratch inside recon region (first ~11 MiB); all dead before recon_mm runs.
  char* scr   = (char*)d_out;
  bf16*  S1T  = (bf16*)(scr + 0);               // [64][8192]    1 MB
  bf16*  h1T  = (bf16*)(scr + (1u << 20));      // [64][8192]    1 MB
  bf16*  W1T  = (bf16*)(scr + (2u << 20));      // [64][256]     32 KB
  float* pP1  = (float*)(scr + (3u << 20));     // [2][8192][64] 4 MB
  float* pP2  = (float*)(scr + (7u << 20));     // [2][8192][64] 4 MB -> ends 11 MiB

  prep_w1t<<<64, 256, 0, stream>>>(W1, W1T);
  // S1T = (x @ W1)^T
  gcn_pass0<<<512, 256, 0, stream>>>(x, 256, W1T, S1T);
  // pP1[by] = adj[:, K-half by] @ s1-half   (1024 blocks, 2x waves/CU)
  gcn_partial<<<dim3(512, 2), 256, 0, stream>>>(adj, N, S1T, pP1);
  // h1T = relu(pP1[0]+pP1[1])^T
  reduce_relu_T<<<128, 256, 0, stream>>>(pP1, h1T);
  // pP2[by] = adj-half @ h1-half
  gcn_partial<<<dim3(512, 2), 256, 0, stream>>>(adj, N, h1T, pP2);
  // mu,lv = (pP2[0]+pP2[1]) @ {W2,W3}
  reduce_w23_mulv<<<128, 256, 0, stream>>>(pP2, W2, W3, mu_out, lv_out);
  // recon = mu @ mu^T
  recon_mm<<<dim3(64, 64), 256, 0, stream>>>(mu_out, recon);
}

// Round 19
// 249.275 us; speedup vs baseline: 1.1277x; 1.1277x over previous
//
#include <hip/hip_runtime.h>

typedef __bf16 bf16;
typedef __attribute__((ext_vector_type(4))) __bf16 bf16x4;
typedef __attribute__((ext_vector_type(8))) __bf16 bf16x8;
typedef __attribute__((ext_vector_type(4))) float f32x4;

#define MFMA16(a, b, c) __builtin_amdgcn_mfma_f32_16x16x32_bf16((a), (b), (c), 0, 0, 0)

constexpr int N   = 8192;
constexpr int HID = 64;

// ---- adj passes: 16 rows/block, 4 waves K-split (Kw=2048), FULL-CONTIGUITY A ----
// A staged in 256-float super-chunks (4 MFMA tiles): 16 instructions, each
// 1KB CONTIGUOUS from one row (lane l -> 16B at row+16l). ra 2-deep chunks,
// rb 2-deep tiles; single 8KB LDS buffer/wave (write c+1 after reads of c,
// per-wave in-order LDS => no barriers). 16B-chunk XOR swizzle, read-conflict-free.
// EPI 1: out = relu(C)^T bf16 ; EPI 2: mu/lv = C @ {W2,W3}.
template <int EPI>
__global__ __launch_bounds__(256) void gcn_adj(const float* __restrict__ A,
                                               const bf16* __restrict__ Bt,
                                               bf16* __restrict__ outT,
                                               const bf16* __restrict__ W23T,
                                               float* __restrict__ mu,
                                               float* __restrict__ lv) {
  __shared__ bf16  As[4][16 * 256];     // 8KB per wave, single buffer
  __shared__ float Hred[4][16][68];
  __shared__ float Ht[16][72];
  const int tid = threadIdx.x, lane = tid & 63, w = tid >> 6;
  const int r = lane & 15, hi = lane >> 4;
  const int i0 = blockIdx.x * 16;
  const int kb0 = w * 2048;             // per-wave K slice (K=8192 fixed)
  constexpr int NSC = 8;                // 2048 / 256 super-chunks

  float4 ra[2][16];                     // 2-deep super-chunks (128 VGPR)
  bf16x8 rb[2][8];                      // 2-deep tile B-fragments (64 VGPR)
  f32x4 acc[4] = {};

  auto loadChunk = [&](float4 (&dst)[16], int c) {
    const int k0 = kb0 + c * 256;
#pragma unroll
    for (int i = 0; i < 16; ++i)        // 1KB contiguous per instruction
      dst[i] = *reinterpret_cast<const float4*>(&A[(size_t)(i0 + i) * N + k0 + lane * 4]);
  };
  auto loadB = [&](bf16x8 (&dst)[8], int T) {  // T = global tile idx (64-k)
    const int k0 = kb0 + T * 64;
#pragma unroll
    for (int n = 0; n < 4; ++n)
#pragma unroll
      for (int kk = 0; kk < 2; ++kk)
        dst[n * 2 + kk] = *reinterpret_cast<const bf16x8*>(
            &Bt[(size_t)(n * 16 + r) * N + k0 + kk * 32 + hi * 8]);
  };
  auto writeChunk = [&](const float4 (&src)[16]) {
    char* base = (char*)&As[w][0];
    const int cl = lane >> 1, bsub = (lane & 1) * 8;
#pragma unroll
    for (int i = 0; i < 16; ++i) {      // row i: 64 lanes hold its 256 floats
      bf16x4 o;
      o[0] = (bf16)src[i].x; o[1] = (bf16)src[i].y;
      o[2] = (bf16)src[i].z; o[3] = (bf16)src[i].w;
      *reinterpret_cast<bf16x4*>(base + i * 512 + (cl ^ (i & 7)) * 16 + bsub) = o;
    }
  };
  auto computeTile = [&](int tt, const bf16x8 (&rbv)[8]) {  // tt = tile in chunk
    const char* base = (const char*)&As[w][0];
#pragma unroll
    for (int kk = 0; kk < 2; ++kk) {
      const int phys = (tt * 8 + kk * 4 + hi) ^ (r & 7);
      const bf16x8 fa = *reinterpret_cast<const bf16x8*>(base + r * 512 + phys * 16);
#pragma unroll
      for (int n = 0; n < 4; ++n)
        acc[n] = MFMA16(fa, rbv[n * 2 + kk], acc[n]);
    }
  };

  // prologue
  loadChunk(ra[0], 0);
  loadChunk(ra[1], 1);
  loadB(rb[0], 0);
  loadB(rb[1], 1);
  writeChunk(ra[0]);                    // chunk 0 -> LDS

#pragma unroll
  for (int c = 0; c < NSC; ++c) {
#pragma unroll
    for (int tt = 0; tt < 4; ++tt) {
      const int T = c * 4 + tt;
      computeTile(tt, rb[T & 1]);
      if (T + 2 < NSC * 4) loadB(rb[T & 1], T + 2);
    }
    if (c + 1 < NSC) writeChunk(ra[(c + 1) & 1]);   // after all reads of chunk c
    if (c + 2 < NSC) loadChunk(ra[c & 1], c + 2);
  }

  // ---- cross-wave K-reduction + epilogue ----
  // C/D layout (m89-verified): col = lane&15, row = (lane>>4)*4 + reg
#pragma unroll
  for (int n = 0; n < 4; ++n)
#pragma unroll
    for (int g = 0; g < 4; ++g)
      Hred[w][hi * 4 + g][n * 16 + r] = acc[n][g];
  __syncthreads();
  {
    const int row = tid >> 4, c4 = (tid & 15) * 4;
    float4 s = {0.f, 0.f, 0.f, 0.f};
#pragma unroll
    for (int q = 0; q < 4; ++q) {
      const float4 v = *reinterpret_cast<const float4*>(&Hred[q][row][c4]);
      s.x += v.x; s.y += v.y; s.z += v.z; s.w += v.w;
    }
    if (EPI == 1) {
      s.x = fmaxf(s.x, 0.f); s.y = fmaxf(s.y, 0.f);
      s.z = fmaxf(s.z, 0.f); s.w = fmaxf(s.w, 0.f);
    }
    *reinterpret_cast<float4*>(&Ht[row][c4]) = s;
  }
  __syncthreads();

  if constexpr (EPI == 1) {
    // transpose-store: outT[j][i0..i0+16], 256 threads
    const int j = tid >> 2, iq = tid & 3;
    bf16x4 o;
#pragma unroll
    for (int e = 0; e < 4; ++e) o[e] = (bf16)Ht[iq * 4 + e][j];
    *reinterpret_cast<bf16x4*>(&outT[(size_t)j * N + i0 + iq * 4]) = o;
  } else {
    // second MFMA: [16][128] = Ht(16x64) @ W23; wave w does q-blocks 2w,2w+1
    f32x4 a2[2] = {};
#pragma unroll
    for (int kk = 0; kk < 2; ++kk) {
      const float4 t0 = *reinterpret_cast<const float4*>(&Ht[r][kk * 32 + hi * 8]);
      const float4 t1 = *reinterpret_cast<const float4*>(&Ht[r][kk * 32 + hi * 8 + 4]);
      bf16x8 fa;
      fa[0] = (bf16)t0.x; fa[1] = (bf16)t0.y; fa[2] = (bf16)t0.z; fa[3] = (bf16)t0.w;
      fa[4] = (bf16)t1.x; fa[5] = (bf16)t1.y; fa[6] = (bf16)t1.z; fa[7] = (bf16)t1.w;
#pragma unroll
      for (int j = 0; j < 2; ++j) {
        const int q = w * 2 + j;
        const bf16x8 fw = *reinterpret_cast<const bf16x8*>(
            &W23T[(size_t)(q * 16 + r) * 64 + kk * 32 + hi * 8]);
        a2[j] = MFMA16(fa, fw, a2[j]);
      }
    }
#pragma unroll
    for (int j = 0; j < 2; ++j) {
      const int q = w * 2 + j;
      float* dst = (q < 4) ? mu : lv;
      const int cc = (q & 3) * 16 + r;
#pragma unroll
      for (int g = 0; g < 4; ++g)
        dst[(size_t)(i0 + hi * 4 + g) * HID + cc] = a2[j][g];
    }
  }
}

// pass0 (K=256): R17 engine, small — unchanged.
__global__ __launch_bounds__(256) void gcn_pass0(const float* __restrict__ A, int K,
                                                 const bf16* __restrict__ Bt,
                                                 bf16* __restrict__ outT) {
  __shared__ bf16  As[4][2][16 * 64];
  __shared__ float Hred[4][16][68];
  __shared__ float Ht[16][72];
  const int tid = threadIdx.x, lane = tid & 63, w = tid >> 6;
  const int r = lane & 15, hi = lane >> 4;
  const int i0 = blockIdx.x * 16;
  const int Kw = K >> 2, kb0 = w * Kw, nt = Kw / 64;
  const int aR = hi, aC = r * 4;

  float4 ra[4][4];
  bf16x8 rb[4][8];
  f32x4 acc[4] = {};

  auto loadA = [&](float4 (&dst)[4], int t) {
    const int k0 = kb0 + t * 64;
#pragma unroll
    for (int s = 0; s < 4; ++s)
      dst[s] = *reinterpret_cast<const float4*>(&A[(size_t)(i0 + 4 * s + aR) * K + k0 + aC]);
  };
  auto loadB = [&](bf16x8 (&dst)[8], int t) {
    const int k0 = kb0 + t * 64;
#pragma unroll
    for (int n = 0; n < 4; ++n)
#pragma unroll
      for (int kk = 0; kk < 2; ++kk)
        dst[n * 2 + kk] = *reinterpret_cast<const bf16x8*>(
            &Bt[(size_t)(n * 16 + r) * K + k0 + kk * 32 + hi * 8]);
  };
  auto writeA = [&](int buf, const float4 (&src)[4]) {
    char* base = (char*)&As[w][buf][0];
#pragma unroll
    for (int s = 0; s < 4; ++s) {
      const int R = 4 * s + aR;
      bf16x4 o;
      o[0] = (bf16)src[s].x; o[1] = (bf16)src[s].y;
      o[2] = (bf16)src[s].z; o[3] = (bf16)src[s].w;
      *reinterpret_cast<bf16x4*>(base + R * 128 + ((aC * 2) ^ ((R & 7) << 4))) = o;
    }
  };
  auto compute = [&](int buf, const bf16x8 (&rbv)[8]) {
    const char* base = (const char*)&As[w][buf][0];
#pragma unroll
    for (int kk = 0; kk < 2; ++kk) {
      const bf16x8 fa = *reinterpret_cast<const bf16x8*>(
          base + r * 128 + ((kk * 64 + hi * 16) ^ ((r & 7) << 4)));
#pragma unroll
      for (int n = 0; n < 4; ++n)
        acc[n] = MFMA16(fa, rbv[n * 2 + kk], acc[n]);
    }
  };

  loadA(ra[0], 0);
  loadB(rb[0], 0);
  writeA(0, ra[0]);
  for (int tb = 0; tb < nt; tb += 4) {
#pragma unroll
    for (int u = 0; u < 4; ++u) {
      const int t = tb + u;
      if (t >= nt) continue;
      if (t + 1 < nt) {
        loadA(ra[(u + 1) & 3], t + 1);
        loadB(rb[(u + 1) & 3], t + 1);
        writeA((u + 1) & 1, ra[(u + 1) & 3]);
      }
      compute(u & 1, rb[u & 3]);
    }
  }

#pragma unroll
  for (int n = 0; n < 4; ++n)
#pragma unroll
    for (int g = 0; g < 4; ++g)
      Hred[w][hi * 4 + g][n * 16 + r] = acc[n][g];
  __syncthreads();
  {
    const int row = tid >> 4, c4 = (tid & 15) * 4;
    float4 s = {0.f, 0.f, 0.f, 0.f};
#pragma unroll
    for (int q = 0; q < 4; ++q) {
      const float4 v = *reinterpret_cast<const float4*>(&Hred[q][row][c4]);
      s.x += v.x; s.y += v.y; s.z += v.z; s.w += v.w;
    }
    *reinterpret_cast<float4*>(&Ht[row][c4]) = s;
  }
  __syncthreads();
  const int j = tid >> 2, iq = tid & 3;
  bf16x4 o;
#pragma unroll
  for (int e = 0; e < 4; ++e) o[e] = (bf16)Ht[iq * 4 + e][j];
  *reinterpret_cast<bf16x4*>(&outT[(size_t)j * N + i0 + iq * 4]) = o;
}

// W1 -> W1T [64][256] bf16 ; W2,W3 -> W23T [128][64] bf16 (single dispatch)
__global__ void prep_weights(const float* __restrict__ W1, const float* __restrict__ W2,
                             const float* __restrict__ W3, bf16* __restrict__ W1T,
                             bf16* __restrict__ W23T) {
  const int idx = blockIdx.x * 256 + threadIdx.x;  // 96 blocks = 24576
  if (idx < 16384) {
    const int j = idx >> 8, k = idx & 255;
    W1T[idx] = (bf16)W1[k * HID + j];
  } else {
    const int g = idx - 16384;                      // 8192
    const int j = g >> 6, c = g & 63;
    W23T[g] = (bf16)(j < 64 ? W2[c * HID + j] : W3[c * HID + (j - 64)]);
  }
}

// recon[i][j] = dot(mu[i,:], mu[j,:]) ; K=64, write-bound.
constexpr int LDT = 72;
__global__ __launch_bounds__(256) void recon_mm(const float* __restrict__ mu,
                                                float* __restrict__ out) {
  __shared__ alignas(16) char pool[128 * LDT * 2 * 2];  // 36864 B: Am|Bm, then Ct
  bf16* Am = (bf16*)pool;                                // [128][72]
  bf16* Bm = (bf16*)(pool + 128 * LDT * 2);              // [128][72]
  float* Ct = (float*)pool;                              // [64][132] = 33792 B
  const int tid = threadIdx.x, lane = tid & 63, wave = tid >> 6;
  const int i0 = blockIdx.x * 128, j0 = blockIdx.y * 128;
  {
    const int rr = tid >> 4, c4 = tid & 15;
#pragma unroll
    for (int s = 0; s < 8; ++s) {
      const int row = rr + s * 16;
      const float4 v = *reinterpret_cast<const float4*>(&mu[(size_t)(i0 + row) * HID + c4 * 4]);
      bf16x4 o;
      o[0] = (bf16)v.x; o[1] = (bf16)v.y; o[2] = (bf16)v.z; o[3] = (bf16)v.w;
      *reinterpret_cast<bf16x4*>(&Am[row * LDT + c4 * 4]) = o;
      const float4 u = *reinterpret_cast<const float4*>(&mu[(size_t)(j0 + row) * HID + c4 * 4]);
      bf16x4 p;
      p[0] = (bf16)u.x; p[1] = (bf16)u.y; p[2] = (bf16)u.z; p[3] = (bf16)u.w;
      *reinterpret_cast<bf16x4*>(&Bm[row * LDT + c4 * 4]) = p;
    }
  }
  __syncthreads();
  f32x4 acc[2][8] = {};
  const int rA = wave * 32 + (lane & 15);
#pragma unroll
  for (int kk = 0; kk < 2; ++kk) {
    const int kb = kk * 32 + ((lane >> 4) << 3);
    const bf16x8 a0 = *reinterpret_cast<const bf16x8*>(&Am[rA * LDT + kb]);
    const bf16x8 a1 = *reinterpret_cast<const bf16x8*>(&Am[(rA + 16) * LDT + kb]);
#pragma unroll
    for (int n = 0; n < 8; ++n) {
      const bf16x8 b = *reinterpret_cast<const bf16x8*>(&Bm[(n * 16 + (lane & 15)) * LDT + kb]);
      acc[0][n] = MFMA16(a0, b, acc[0][n]);
      acc[1][n] = MFMA16(a1, b, acc[1][n]);
    }
  }
  const int r4 = (lane >> 4) << 2, c = lane & 15;
#pragma unroll
  for (int h = 0; h < 2; ++h) {
    __syncthreads();
    if ((wave >> 1) == h) {
      const int rbase = (wave & 1) * 32;
#pragma unroll
      for (int m = 0; m < 2; ++m)
#pragma unroll
        for (int n = 0; n < 8; ++n)
#pragma unroll
          for (int g = 0; g < 4; ++g)
            Ct[(rbase + m * 16 + r4 + g) * 132 + n * 16 + c] = acc[m][n][g];
    }
    __syncthreads();
#pragma unroll
    for (int s = 0; s < 8; ++s) {
      const int idx = tid + s * 256;
      const int row = idx >> 5, q = idx & 31;
      const float4 v = *reinterpret_cast<const float4*>(&Ct[row * 132 + q * 4]);
      *reinterpret_cast<float4*>(&out[(size_t)(i0 + h * 64 + row) * N + j0 + q * 4]) = v;
    }
  }
}

extern "C" void kernel_launch(void* const* d_in, const int* in_sizes, int n_in, void* d_out,
                              int out_size, void* d_ws, size_t ws_size, hipStream_t stream) {
  const float* x   = (const float*)d_in[0];
  const float* adj = (const float*)d_in[1];
  const float* W1  = (const float*)d_in[2];
  const float* W2  = (const float*)d_in[3];
  const float* W3  = (const float*)d_in[4];

  float* out    = (float*)d_out;
  float* recon  = out;                          // [8192][8192] 256 MiB
  float* mu_out = out + (size_t)N * N;          // outside recon region
  float* lv_out = mu_out + (size_t)N * HID;

  // Scratch inside recon region (first ~3 MiB); all dead before recon_mm runs.
  char* scr   = (char*)d_out;
  bf16* S1T   = (bf16*)(scr + 0);               // [64][8192]  1 MB
  bf16* h1T   = (bf16*)(scr + (1u << 20));      // [64][8192]  1 MB
  bf16* W1T   = (bf16*)(scr + (2u << 20));      // [64][256]   32 KB
  bf16* W23T  = (bf16*)(scr + (2u << 20) + 65536);  // [128][64] 16 KB

  prep_weights<<<96, 256, 0, stream>>>(W1, W2, W3, W1T, W23T);
  // S1T = (x @ W1)^T
  gcn_pass0<<<512, 256, 0, stream>>>(x, 256, W1T, S1T);
  // h1T = relu(adj @ s1)^T   (1KB-contiguous A loads)
  gcn_adj<1><<<512, 256, 0, stream>>>(adj, S1T, h1T, nullptr, nullptr, nullptr);
  // mu, lv = (adj @ h1) @ {W2,W3}
  gcn_adj<2><<<512, 256, 0, stream>>>(adj, h1T, nullptr, W23T, mu_out, lv_out);
  // recon = mu @ mu^T
  recon_mm<<<dim3(64, 64), 256, 0, stream>>>(mu_out, recon);
}